// Round 8
// baseline (41.054 us; speedup 1.0000x reference)
//
#include <hip/hip_runtime.h>
#include <hip/hip_bf16.h>

#define BB 256
#define NGT 8
#define HWA 10647
#define NTH 1024
#define NREG 11          // ceil(HWA/NTH)
#define CAP 1024
#define NAB 96           // above-boundary count < k <= 72
#define EPSF 1e-6f
#define FP16_EPS 0.0009765625f

// exact reference value: -log1p(-clip(sigmoid(x)))
__device__ __forceinline__ float lv_exact(float x) {
    float s = 1.f / (1.f + expf(-x));
    s = fminf(fmaxf(s, EPSF), 1.f - EPSF);
    return -log1pf(-s);
}
// order-monotone unsigned key for float compare
__device__ __forceinline__ unsigned fkey(float x) {
    const unsigned u = __float_as_uint(x);
    return u ^ ((u & 0x80000000u) ? 0xFFFFFFFFu : 0x80000000u);
}

__global__ __launch_bounds__(NTH) void yolo_loss_fused(
    const float* __restrict__ pconf, const float* __restrict__ pcls,
    const float* __restrict__ ptxywh, const float* __restrict__ gboxes,
    const int* __restrict__ glabels, float* __restrict__ partial,
    unsigned* __restrict__ counter, float* __restrict__ out)
{
    const int b = blockIdx.x;
    const int tid = threadIdx.x;
    const int lane = tid & 63;
    const int wv = tid >> 6;

    __shared__ int   hist[256];
    __shared__ int   hist2[256];
    __shared__ float cand[CAP];
    __shared__ float sab[NAB];
    __shared__ int   s_idx[NGT];
    __shared__ float s_row[NGT][13];
    __shared__ int   s_mpos[3 * NGT];
    __shared__ int   s_npos, s_nm, s_ccount, s_nab, s_last;
    __shared__ float fred[16];

    // snapshot arrival counter first (all 256 blocks co-resident: 1 block/CU)
    unsigned snap = 0;
    if (tid == 0)
        snap = __hip_atomic_load(counter, __ATOMIC_RELAXED, __HIP_MEMORY_SCOPE_AGENT);

    // ---- issue global loads early ----
    float gl = 0.f, gt = 0.f, gr = 0.f, gbo = 0.f;
    int lab = 0;
    if (tid < NGT) {
        const float* gb = gboxes + ((size_t)b * NGT + tid) * 4;
        gl = gb[0]; gt = gb[1]; gr = gb[2]; gbo = gb[3];
        lab = glabels[b * NGT + tid] - 1;
    }
    const float* pc = pconf + (size_t)b * HWA;
    float x[NREG];
#pragma unroll
    for (int v = 0; v < NREG; ++v) {
        const int p = tid + v * NTH;
        x[v] = (p < HWA) ? pc[p] : 0.f;
    }
    if (tid < 256) { hist[tid] = 0; hist2[tid] = 0; }
    if (tid == 0)  { s_npos = 0; s_nm = 0; s_ccount = 0; s_nab = 0; }

    // ---- Phase A: per-GT matching (threads 0..7) ----
    if (tid < NGT) {
        const float cx = (gl + gr) * 0.5f, cy = (gt + gbo) * 0.5f;
        const float w = gr - gl, h = gbo - gt;
        const float area_g = w * h;
        const float AW[9] = {0.0276f, 0.0386f, 0.0795f, 0.0721f, 0.1495f, 0.1421f, 0.2788f, 0.375f, 0.897f};
        const float AH[9] = {0.0361f, 0.0697f, 0.0553f, 0.1466f, 0.1087f, 0.2861f, 0.2163f, 0.476f, 0.784f};
        float best = -1.f, baw = AW[0], bah = AH[0];
        int id = 0;
#pragma unroll
        for (int a = 0; a < 9; ++a) {
            float inter = fminf(w, AW[a]) * fminf(h, AH[a]);
            float iou = inter / (area_g + AW[a] * AH[a] - inter);
            if (iou > best) { best = iou; id = a; baw = AW[a]; bah = AH[a]; }
        }
        const int ceng = id / 3, anc = id % 3;
        const int grid = (ceng == 0) ? 52 : ((ceng == 1) ? 26 : 13);
        const int coff = (ceng == 0) ? 0 : ((ceng == 1) ? 8112 : 10140);
        const float gf = (float)grid;
        const int col = (int)(cx * gf);
        const int row = (int)(cy * gf);
        s_idx[tid] = coff + (row * grid + col) * 3 + anc;
        float* rr = s_row[tid];
        rr[0] = 1.f;
        rr[1] = (lab == 0) ? 1.f : 0.f;
        rr[2] = (lab == 1) ? 1.f : 0.f;
        rr[3] = (lab == 2) ? 1.f : 0.f;
        rr[4] = (cx - (float)col / gf) * gf;
        rr[5] = (cy - (float)row / gf) * gf;
        rr[6] = logf(w / baw);
        rr[7] = logf(h / bah);
        rr[8] = 2.f - area_g;
        rr[9] = gl; rr[10] = gt; rr[11] = gr; rr[12] = gbo;
    }
    __syncthreads();   // B1: s_idx/s_row ready, hists zeroed

    int idxr[NGT];
#pragma unroll
    for (int j = 0; j < NGT; ++j) idxr[j] = s_idx[j];

    float psum = 0.f;  // this thread's share of every loss term

    // ---- Phase A2 (threads 0..23): scatter replay, masked-pos list,
    //      hist fix-up (subtract masked keys), positive loss terms ----
    if (tid < 3 * NGT) {
        const int i = tid / 3, d = tid % 3;
        const int p = idxr[i] + d;
        if (p < HWA) {                    // OOB scatter dropped by JAX
            bool canon = true;
            for (int c2 = 0; c2 < tid; ++c2)
                if (idxr[c2 / 3] + (c2 % 3) == p) { canon = false; break; }
            int conf = 0, src = -1;
#pragma unroll
            for (int j = 0; j < NGT; ++j) {
                const int dj = p - idxr[j];
                if (dj >= 0 && dj < 3) conf = -1;     // ignore-mark col0
                if (dj == 0) { conf = 1; src = j; }   // full-row set
            }
            if (canon) {
                s_mpos[atomicAdd(&s_nm, 1)] = p;
                const float xp = pc[p];
                atomicAdd(&hist[fkey(xp) >> 24], -1);   // cancel Phase B's add
                if (conf == 1) {
                    atomicAdd(&s_npos, 1);
                    // positive-position loss terms
                    const float* rr = s_row[src];
                    float acc = -logf(fminf(fmaxf(1.f / (1.f + expf(-xp)), EPSF), 1.f - EPSF));
                    const float* pcl = pcls + ((size_t)b * HWA + p) * 3;
#pragma unroll
                    for (int cc = 0; cc < 3; ++cc) {
                        const float sc = fminf(fmaxf(1.f / (1.f + expf(-pcl[cc])), EPSF), 1.f - EPSF);
                        const float g = rr[1 + cc];
                        acc += -(g * logf(sc) + (1.f - g) * log1pf(-sc));
                    }
                    const float* pt = ptxywh + ((size_t)b * HWA + p) * 4;
                    const float wgt = rr[8];
                    float a2 = 0.f;
#pragma unroll
                    for (int cc = 0; cc < 2; ++cc) {
                        const float st = fminf(fmaxf(1.f / (1.f + expf(-pt[cc])), EPSF), 1.f - EPSF);
                        const float g = rr[4 + cc];
                        a2 += -(g * logf(st) + (1.f - g) * log1pf(-st));
                    }
                    acc += a2 * wgt;
                    const float d0 = pt[2] - rr[6], d1 = pt[3] - rr[7];
                    acc += (d0 * d0 + d1 * d1) * wgt;
                    psum += acc;
                }
            }
        }
    }

    // ---- Phase B: unconditional key histogram (no mask test) ----
#pragma unroll
    for (int v = 0; v < NREG; ++v) {
        const int p = tid + v * NTH;
        if (p < HWA) atomicAdd(&hist[fkey(x[v]) >> 24], 1);
    }
    __syncthreads();   // B2: hist (incl. fix-up) + npos + mpos final

    const int npos = s_npos;
    const float nums_pos = fmaxf((float)npos, FP16_EPS);
    const int k = (npos > 0) ? (3 * npos) : 1;
    const int nm = s_nm;

    // ---- replicated per-wave suffix scan over hist (no barriers) ----
    int bStar, above1, cbin;
    {
        const int h0 = hist[4 * lane + 0], h1 = hist[4 * lane + 1];
        const int h2 = hist[4 * lane + 2], h3 = hist[4 * lane + 3];
        const int s3 = h3, s2 = h2 + s3, s1 = h1 + s2, s0 = h0 + s1;
        int t = s0;
#pragma unroll
        for (int off = 1; off < 64; off <<= 1) {
            const int o = __shfl_down(t, off, 64);
            t += (lane + off < 64) ? o : 0;
        }
        const int aw = t - s0;              // count in lanes > lane
        int fbin = 0, fsa = 0, fcb = 0;
        bool found = false;
        const int a0 = aw + s1, a1 = aw + s2, a2 = aw + s3, a3 = aw;
        if (a0 < k && a0 + h0 >= k) { fbin = 4 * lane + 0; fsa = a0; fcb = h0; found = true; }
        if (a1 < k && a1 + h1 >= k) { fbin = 4 * lane + 1; fsa = a1; fcb = h1; found = true; }
        if (a2 < k && a2 + h2 >= k) { fbin = 4 * lane + 2; fsa = a2; fcb = h2; found = true; }
        if (a3 < k && a3 + h3 >= k) { fbin = 4 * lane + 3; fsa = a3; fcb = h3; found = true; }
        const unsigned long long bm = __ballot(found);
        const int src = __ffsll(bm) - 1;
        bStar  = __shfl(fbin, src, 64);
        above1 = __shfl(fsa,  src, 64);
        cbin   = __shfl(fcb,  src, 64);
    }
    const bool fits = (cbin <= CAP);

    // ---- gather above-boundary + boundary-bin (masked excluded) ----
#pragma unroll
    for (int v = 0; v < NREG; ++v) {
        const int p = tid + v * NTH;
        if (p < HWA) {
            const int kb = (int)(fkey(x[v]) >> 24);
            if (kb >= bStar) {
                bool masked = false;
                for (int q = 0; q < nm; ++q) masked = masked || (s_mpos[q] == p);
                if (!masked) {
                    if (kb > bStar) sab[atomicAdd(&s_nab, 1)] = x[v];
                    else if (fits)  cand[atomicAdd(&s_ccount, 1)] = x[v];
                    else atomicAdd(&hist2[(fkey(x[v]) >> 16) & 0xff], 1);
                }
            }
        }
    }
    __syncthreads();   // B5: sab/cand (or hist2) ready

    // compacted libm for above-boundary values (< k <= 72)
    for (int t2 = tid; t2 < s_nab; t2 += NTH) psum += lv_exact(sab[t2]);

    int rneed;
    if (fits) {
        rneed = k - above1;
    } else {
        // rare fallback: refine by next 8 key bits (replicated wave scan again)
        int mStar, aboveF;
        {
            const int h0 = hist2[4 * lane + 0], h1 = hist2[4 * lane + 1];
            const int h2 = hist2[4 * lane + 2], h3 = hist2[4 * lane + 3];
            const int s3 = h3, s2 = h2 + s3, s1 = h1 + s2, s0 = h0 + s1;
            int t = s0;
#pragma unroll
            for (int off = 1; off < 64; off <<= 1) {
                const int o = __shfl_down(t, off, 64);
                t += (lane + off < 64) ? o : 0;
            }
            const int aw = t - s0;
            int fbin = 0, fsa = 0;
            bool found = false;
            const int a0 = above1 + aw + s1, a1 = above1 + aw + s2;
            const int a2 = above1 + aw + s3, a3 = above1 + aw;
            if (a0 < k && a0 + h0 >= k) { fbin = 4 * lane + 0; fsa = a0; found = true; }
            if (a1 < k && a1 + h1 >= k) { fbin = 4 * lane + 1; fsa = a1; found = true; }
            if (a2 < k && a2 + h2 >= k) { fbin = 4 * lane + 2; fsa = a2; found = true; }
            if (a3 < k && a3 + h3 >= k) { fbin = 4 * lane + 3; fsa = a3; found = true; }
            const unsigned long long bm = __ballot(found);
            const int src = __ffsll(bm) - 1;
            mStar  = __shfl(fbin, src, 64);
            aboveF = __shfl(fsa,  src, 64);
        }
#pragma unroll
        for (int v = 0; v < NREG; ++v) {
            const int p = tid + v * NTH;
            if (p < HWA) {
                const unsigned kk = fkey(x[v]);
                if ((int)(kk >> 24) == bStar) {
                    bool masked = false;
                    for (int q = 0; q < nm; ++q) masked = masked || (s_mpos[q] == p);
                    if (!masked) {
                        const int mb = (int)((kk >> 16) & 0xff);
                        if (mb > mStar) psum += lv_exact(x[v]);
                        else if (mb == mStar) {
                            const int c = atomicAdd(&s_ccount, 1);
                            if (c < CAP) cand[c] = x[v];
                        }
                    }
                }
            }
        }
        __syncthreads();
        rneed = k - aboveF;
    }

    // ---- one-shot rank select over boundary candidates ----
    const int C = min(s_ccount, CAP);
    for (int t2 = tid; t2 < C; t2 += NTH) {
        const float v = cand[t2];
        int rank = 0;
        for (int j = 0; j < C; ++j) {
            const float w = cand[j];
            rank += (w > v) || (w == v && j < t2);
        }
        if (rank < rneed) psum += lv_exact(v);
    }

    // ---- deterministic block reduction ----
    {
        float v = psum;
#pragma unroll
        for (int off = 32; off > 0; off >>= 1) v += __shfl_down(v, off, 64);
        if (lane == 0) fred[wv] = v;
    }
    __syncthreads();   // B6
    if (tid == 0) {
        float t = 0.f;
#pragma unroll
        for (int w = 0; w < 16; ++w) t += fred[w];
        __hip_atomic_store(&partial[b], t / nums_pos,
                           __ATOMIC_RELEASE, __HIP_MEMORY_SCOPE_AGENT);
        // snapshot last-arrival (base-independent, no reset node needed):
        // all snapshots precede any increment (blocks co-resident), so old
        // values are {base..base+255} and exactly old==snap+255 triggers.
        const unsigned old = __hip_atomic_fetch_add(counter, 1u,
                           __ATOMIC_ACQ_REL, __HIP_MEMORY_SCOPE_AGENT);
        s_last = (old == snap + 255u) ? 1 : 0;
    }
    __syncthreads();   // B7: s_last visible

    // ---- last-arriving block: fixed-order final reduction ----
    if (s_last) {
        float v = 0.f;
        if (tid < BB)
            v = __hip_atomic_load(&partial[tid], __ATOMIC_ACQUIRE,
                                  __HIP_MEMORY_SCOPE_AGENT);
#pragma unroll
        for (int off = 32; off > 0; off >>= 1) v += __shfl_down(v, off, 64);
        if (lane == 0) fred[wv] = v;
        __syncthreads();
        if (tid == 0) {
            float s = 0.f;
#pragma unroll
            for (int w = 0; w < 16; ++w) s += fred[w];
            out[0] = s * (1.f / (float)BB);
        }
    }
}

extern "C" void kernel_launch(void* const* d_in, const int* in_sizes, int n_in,
                              void* d_out, int out_size, void* d_ws, size_t ws_size,
                              hipStream_t stream) {
    const float* pconf   = (const float*)d_in[0];
    const float* pcls    = (const float*)d_in[1];
    const float* ptxywh  = (const float*)d_in[2];
    const float* gboxes  = (const float*)d_in[3];
    const int*   glabels = (const int*)d_in[4];
    float* out = (float*)d_out;
    float* partial = (float*)d_ws;                         // 256 floats
    unsigned* counter = (unsigned*)((char*)d_ws + 1024);   // 1 u32 (never reset)

    yolo_loss_fused<<<BB, NTH, 0, stream>>>(pconf, pcls, ptxywh, gboxes,
                                            glabels, partial, counter, out);
}